// Round 1
// baseline (4037.936 us; speedup 1.0000x reference)
//
#include <hip/hip_runtime.h>
#include <hip/hip_bf16.h>
#include <stdint.h>

#define SEQ   512
#define BATCH 1024
#define IN_F  256
#define HID   512
#define OUT_F 64

// ws layout (bytes)
static const size_t OFF_V   = 0;            // 1024*512*4   = 2 MB
static const size_t OFF_I   = 2097152;      // 2 MB
static const size_t OFF_VO  = 4194304;      // 1024*64*4    = 256 KB
static const size_t OFF_IO  = 4456448;      // 256 KB
static const size_t OFF_ZM  = 4718592;      // 1024*8*8     = 64 KB
static const size_t OFF_WRT = 4784128;      // 513*512*4    = 1.002 MB (row 512 = zeros)
static const size_t OFF_WOT = 5834752;      // 512*64*2     = 64 KB (bf16)
static const size_t OFF_CUR = 5900288;      // chunk of cur, csteps*1024*512*4

__global__ void init_state_kernel(float4* __restrict__ p, int n4) {
    int i = blockIdx.x * blockDim.x + threadIdx.x;
    int stride = gridDim.x * blockDim.x;
    float4 z = make_float4(0.f, 0.f, 0.f, 0.f);
    for (; i < n4; i += stride) p[i] = z;
}

__global__ void prep_kernel(const float* __restrict__ wrec, const float* __restrict__ wout,
                            float* __restrict__ wrecT, __hip_bfloat16* __restrict__ woutT) {
    int i = blockIdx.x * blockDim.x + threadIdx.x;
    int stride = gridDim.x * blockDim.x;
    for (int idx = i; idx < 513 * 512; idx += stride) {
        int j = idx >> 9, h = idx & 511;
        wrecT[idx] = (j < 512) ? wrec[h * 512 + j] : 0.0f;   // wrecT[j][h] = w_rec[h][j]
    }
    for (int idx = i; idx < 512 * 64; idx += stride) {
        int h = idx >> 6, o = idx & 63;
        woutT[idx] = __float2bfloat16(wout[o * 512 + h]);     // woutT[h][o] = w_out[o][h]
    }
}

// C[m][n] = sum_k A[m][k] * B[n][k];  A:[Mc][256] B:[512][256] C:[Mc][512]
__launch_bounds__(256)
__global__ void gemm_kernel(const float* __restrict__ A, const float* __restrict__ Bw,
                            float* __restrict__ C) {
    __shared__ float As[16 * 64];
    __shared__ float Bs[16 * 64];
    const int t = threadIdx.x;
    const size_t m0 = (size_t)blockIdx.x * 64;
    const int n0 = blockIdx.y * 64;
    const int tn = t & 15, tm = t >> 4;      // 16x16 thread grid, 4x4 microtile
    const int lm = t >> 2, lk = (t & 3) << 2;
    const float* Ap = A + (m0 + (size_t)lm) * IN_F + lk;
    const float* Bp = Bw + (size_t)(n0 + lm) * IN_F + lk;
    float acc[4][4] = {{0.f}};
    for (int k0 = 0; k0 < IN_F; k0 += 16) {
        float4 a4 = *(const float4*)(Ap + k0);
        float4 b4 = *(const float4*)(Bp + k0);
        __syncthreads();
        As[(lk + 0) * 64 + lm] = a4.x;
        As[(lk + 1) * 64 + lm] = a4.y;
        As[(lk + 2) * 64 + lm] = a4.z;
        As[(lk + 3) * 64 + lm] = a4.w;
        Bs[(lk + 0) * 64 + lm] = b4.x;
        Bs[(lk + 1) * 64 + lm] = b4.y;
        Bs[(lk + 2) * 64 + lm] = b4.z;
        Bs[(lk + 3) * 64 + lm] = b4.w;
        __syncthreads();
        #pragma unroll
        for (int k = 0; k < 16; ++k) {
            float4 av = *(const float4*)&As[k * 64 + 4 * tm];
            float4 bv = *(const float4*)&Bs[k * 64 + 4 * tn];
            acc[0][0] += av.x * bv.x; acc[0][1] += av.x * bv.y; acc[0][2] += av.x * bv.z; acc[0][3] += av.x * bv.w;
            acc[1][0] += av.y * bv.x; acc[1][1] += av.y * bv.y; acc[1][2] += av.y * bv.z; acc[1][3] += av.y * bv.w;
            acc[2][0] += av.z * bv.x; acc[2][1] += av.z * bv.y; acc[2][2] += av.z * bv.z; acc[2][3] += av.z * bv.w;
            acc[3][0] += av.w * bv.x; acc[3][1] += av.w * bv.y; acc[3][2] += av.w * bv.z; acc[3][3] += av.w * bv.w;
        }
    }
    float* Cp = C + (m0 + (size_t)(4 * tm)) * HID + n0 + 4 * tn;
    #pragma unroll
    for (int r = 0; r < 4; ++r) {
        float4 cv = make_float4(acc[r][0], acc[r][1], acc[r][2], acc[r][3]);
        *(float4*)(Cp + (size_t)r * HID) = cv;
    }
}

// One block per batch element; 512 threads (thread = hidden unit h).
__launch_bounds__(512)
__global__ void rec_kernel(const float* __restrict__ cur,
                           const float* __restrict__ wrecT,
                           const __hip_bfloat16* __restrict__ woutTg,
                           float* __restrict__ stV, float* __restrict__ stI,
                           float* __restrict__ stVO, float* __restrict__ stIO,
                           unsigned long long* __restrict__ stZM,
                           float* __restrict__ out, int t0, int csteps) {
    __shared__ __attribute__((aligned(16))) __hip_bfloat16 woutT_lds[512 * 64]; // 64 KB
    __shared__ __attribute__((aligned(16))) unsigned short slist[2][528];
    __shared__ unsigned long long zm[8];
    __shared__ float ypart[8][64];

    const int b = blockIdx.x;
    const int tid = threadIdx.x;
    const int lane = tid & 63;
    const int w = tid >> 6;

    {   // stage w_out^T (bf16) into LDS
        const uint4* src = (const uint4*)woutTg;
        uint4* dst = (uint4*)woutT_lds;
        for (int i = tid; i < 4096; i += 512) dst[i] = src[i];
    }
    float v  = stV[b * HID + tid];
    float ii = stI[b * HID + tid];
    float vo = 0.f, io = 0.f;
    if (tid < OUT_F) { vo = stVO[b * OUT_F + tid]; io = stIO[b * OUT_F + tid]; }
    if (tid < 8) zm[tid] = stZM[b * 8 + tid];
    __syncthreads();

    int cnt, cpad;
    {   // initial spike list (buffer 0) from persisted masks
        unsigned long long mm[8];
        #pragma unroll
        for (int q = 0; q < 8; ++q) mm[q] = zm[q];
        int pre = 0, total = 0;
        #pragma unroll
        for (int q = 0; q < 8; ++q) { int pc = (int)__popcll(mm[q]); total += pc; if (q < w) pre += pc; }
        int below = (int)__popcll(mm[w] & ((1ull << lane) - 1ull));
        int spike0 = (int)((mm[w] >> lane) & 1ull);
        if (spike0) slist[0][pre + below] = (unsigned short)tid;
        cnt = total; cpad = (cnt + 7) & ~7;
        if (tid < 8 && cnt + tid < cpad) slist[0][cnt + tid] = (unsigned short)HID;
    }
    __syncthreads();

    int cb = 0;
    for (int tl = 0; tl < csteps; ++tl) {
        float cur_v = cur[((size_t)tl * BATCH + b) * HID + tid];
        // recurrent input: sum of wrecT rows for previous step's spikes (pad rows are zero)
        float rec = 0.f;
        for (int k = 0; k < cpad; k += 8) {
            uint4 pk = *(const uint4*)&slist[cb][k];
            int j0 = pk.x & 0xffff, j1 = pk.x >> 16;
            int j2 = pk.y & 0xffff, j3 = pk.y >> 16;
            int j4 = pk.z & 0xffff, j5 = pk.z >> 16;
            int j6 = pk.w & 0xffff, j7 = pk.w >> 16;
            rec += wrecT[j0 * HID + tid];
            rec += wrecT[j1 * HID + tid];
            rec += wrecT[j2 * HID + tid];
            rec += wrecT[j3 * HID + tid];
            rec += wrecT[j4 * HID + tid];
            rec += wrecT[j5 * HID + tid];
            rec += wrecT[j6 * HID + tid];
            rec += wrecT[j7 * HID + tid];
        }
        // LIF update (expression forms mirror the reference)
        float vdec = v + 0.1f * ((0.0f - v) + ii);
        int spike = (vdec > 1.0f) ? 1 : 0;
        v = spike ? 0.0f : vdec;
        float idec = ii + 0.2f * (0.0f - ii);
        ii = (idec + cur_v) + rec;

        unsigned long long m = __ballot(spike);
        if (lane == 0) zm[w] = m;
        __syncthreads();                                   // (1) masks visible
        {   // build new spike list into slist[cb^1]
            unsigned long long mm[8];
            #pragma unroll
            for (int q = 0; q < 8; ++q) mm[q] = zm[q];
            int pre = 0, total = 0;
            #pragma unroll
            for (int q = 0; q < 8; ++q) { int pc = (int)__popcll(mm[q]); total += pc; if (q < w) pre += pc; }
            int below = (int)__popcll(mm[w] & ((1ull << lane) - 1ull));
            if (spike) slist[cb ^ 1][pre + below] = (unsigned short)tid;
            cnt = total; cpad = (cnt + 7) & ~7;
            if (tid < 8 && cnt + tid < cpad) slist[cb ^ 1][cnt + tid] = (unsigned short)HID;
        }
        __syncthreads();                                   // (2) list visible
        {   // readout y = z_new @ w_out^T, split across 8 waves
            float yp = 0.f;
            for (int k = w; k < cnt; k += 8) {
                int hh = slist[cb ^ 1][k];
                yp += __bfloat162float(woutT_lds[hh * OUT_F + lane]);
            }
            ypart[w][lane] = yp;
        }
        __syncthreads();                                   // (3) partials visible
        if (tid < OUT_F) {
            float y = 0.f;
            #pragma unroll
            for (int q = 0; q < 8; ++q) y += ypart[q][tid];
            float von = vo + 0.1f * ((0.0f - vo) + io);
            float iodec = io + 0.2f * (0.0f - io);
            io = iodec + y;
            vo = von;
            out[(((size_t)(t0 + tl)) * BATCH + b) * OUT_F + tid] = von;
        }
        cb ^= 1;
    }
    stV[b * HID + tid] = v;
    stI[b * HID + tid] = ii;
    if (tid < OUT_F) { stVO[b * OUT_F + tid] = vo; stIO[b * OUT_F + tid] = io; }
    if (tid < 8) stZM[b * 8 + tid] = zm[tid];
}

extern "C" void kernel_launch(void* const* d_in, const int* in_sizes, int n_in,
                              void* d_out, int out_size, void* d_ws, size_t ws_size,
                              hipStream_t stream) {
    const float* x     = (const float*)d_in[0];
    const float* w_in  = (const float*)d_in[1];
    const float* w_rec = (const float*)d_in[2];
    const float* w_out = (const float*)d_in[3];
    float* out = (float*)d_out;
    char* ws = (char*)d_ws;

    float* stV  = (float*)(ws + OFF_V);
    float* stI  = (float*)(ws + OFF_I);
    float* stVO = (float*)(ws + OFF_VO);
    float* stIO = (float*)(ws + OFF_IO);
    unsigned long long* stZM = (unsigned long long*)(ws + OFF_ZM);
    float* wrecT = (float*)(ws + OFF_WRT);
    __hip_bfloat16* woutT = (__hip_bfloat16*)(ws + OFF_WOT);
    float* curbuf = (float*)(ws + OFF_CUR);

    // pick chunk size (steps) that fits the scratch buffer; divides 512
    size_t cap = (ws_size > OFF_CUR) ? (ws_size - OFF_CUR) : 0;
    int csteps = 1;
    for (int c = 512; c >= 1; c >>= 1) {
        if ((size_t)c * (size_t)BATCH * HID * 4 <= cap) { csteps = c; break; }
    }

    // init persistent state (v,i,vo,io,zmask all zero)
    {
        int n4 = (int)(OFF_WRT / 16);
        int blocks = (n4 + 255) / 256;
        if (blocks > 4096) blocks = 4096;
        hipLaunchKernelGGL(init_state_kernel, dim3(blocks), dim3(256), 0, stream,
                           (float4*)ws, n4);
    }
    hipLaunchKernelGGL(prep_kernel, dim3(512), dim3(256), 0, stream,
                       w_rec, w_out, wrecT, woutT);

    for (int t0 = 0; t0 < SEQ; t0 += csteps) {
        hipLaunchKernelGGL(gemm_kernel, dim3(csteps * (BATCH / 64), HID / 64), dim3(256), 0, stream,
                           x + (size_t)t0 * BATCH * IN_F, w_in, curbuf);
        hipLaunchKernelGGL(rec_kernel, dim3(BATCH), dim3(512), 0, stream,
                           curbuf, wrecT, woutT, stV, stI, stVO, stIO, stZM, out, t0, csteps);
    }
}